// Round 1
// baseline (664.371 us; speedup 1.0000x reference)
//
#include <hip/hip_runtime.h>
#include <math.h>

// Router: logits = z @ W^T + b ; top-2 sparse softmax per row.
// z: [N=8192, D=4096] fp32, W: [K=64, D=4096] fp32, b: [64] fp32, k=2.
// out: alpha [N, 64] fp32 (zeros except top-2 columns per row).
//
// Design: lane = output column (K=64 == wave size). Each wave computes 8 rows.
// W chunk staged in LDS (reused by all 32 rows of the block); z read directly
// from global with wave-uniform (broadcast) float4 loads. fp32 accumulation
// (2 interleaved chains per row) -> ~1e-6 logit accuracy so the top-2
// selection matches the fp32 numpy reference.

constexpr int D_DIM = 4096;
constexpr int K_DIM = 64;
constexpr int BK    = 64;            // D-chunk per LDS stage
constexpr int RM    = 8;             // rows per wave
constexpr int WAVES = 4;
constexpr int BM    = RM * WAVES;    // 32 rows per block
constexpr int BLOCK = WAVES * 64;    // 256 threads

__global__ __launch_bounds__(BLOCK) void router_kernel(
    const float* __restrict__ z, const float* __restrict__ W,
    const float* __restrict__ bias, float* __restrict__ out)
{
    __shared__ float wtile[K_DIM][BK + 4];     // +4 keeps float4 alignment
    __shared__ float slog[BM][K_DIM + 1];
    __shared__ float s_a1[BM], s_a2[BM];
    __shared__ int   s_i1[BM], s_i2[BM];

    const int tid  = threadIdx.x;
    const int lane = tid & 63;                 // = output column
    const int wave = tid >> 6;
    const long row0 = (long)blockIdx.x * BM + (long)wave * RM;
    const float* zbase = z + row0 * D_DIM;

    float accA[RM], accB[RM];
#pragma unroll
    for (int r = 0; r < RM; ++r) { accA[r] = 0.f; accB[r] = 0.f; }

    for (int d0 = 0; d0 < D_DIM; d0 += BK) {
        // Stage W[0:64][d0:d0+BK] -> wtile, fully coalesced (16B/lane).
#pragma unroll
        for (int i = 0; i < (K_DIM * BK) / (BLOCK * 4); ++i) {   // 4 iters
            int f = tid + i * BLOCK;       // float4 index in [0,1024)
            int k = f >> 4;                // 16 float4 per W row chunk
            int j = (f & 15) * 4;
            const float4 v = *(const float4*)(W + (long)k * D_DIM + d0 + j);
            float* dst = &wtile[k][j];
            dst[0] = v.x; dst[1] = v.y; dst[2] = v.z; dst[3] = v.w;
        }
        __syncthreads();

#pragma unroll
        for (int q = 0; q < BK / 4; ++q) {
            const float4 wv = *(const float4*)&wtile[lane][q * 4];
            const float* zp = zbase + d0 + q * 4;
#pragma unroll
            for (int r = 0; r < RM; ++r) {
                // wave-uniform address: one broadcast 16B request per wave
                const float4 zv = *(const float4*)(zp + (long)r * D_DIM);
                accA[r] = fmaf(wv.x, zv.x, accA[r]);
                accB[r] = fmaf(wv.y, zv.y, accB[r]);
                accA[r] = fmaf(wv.z, zv.z, accA[r]);
                accB[r] = fmaf(wv.w, zv.w, accB[r]);
            }
        }
        __syncthreads();
    }

    // logits -> LDS (+bias)
    const float bv = bias[lane];
#pragma unroll
    for (int r = 0; r < RM; ++r)
        slog[wave * RM + r][lane] = accA[r] + accB[r] + bv;
    __syncthreads();

    // per-row top-2 + 2-term softmax (others underflow to exact 0)
    if (tid < BM) {
        float m1 = -INFINITY, m2 = -INFINITY;
        int i1 = 0, i2 = 0;
        for (int j = 0; j < K_DIM; ++j) {
            float v = slog[tid][j];
            if (v > m1)      { m2 = m1; i2 = i1; m1 = v; i1 = j; }
            else if (v > m2) { m2 = v; i2 = j; }
        }
        float e2  = expf(m2 - m1);
        float inv = 1.f / (1.f + e2);
        s_a1[tid] = inv;
        s_a2[tid] = e2 * inv;
        s_i1[tid] = i1; s_i2[tid] = i2;
    }
    __syncthreads();

    // coalesced float4 store of the sparse alpha tile
    float* obase = out + (long)blockIdx.x * (BM * K_DIM);
#pragma unroll
    for (int i = 0; i < (BM * K_DIM) / (BLOCK * 4); ++i) {       // 2 iters
        int f   = tid + i * BLOCK;        // float4 idx in [0,512)
        int row = f >> 4;
        int j   = (f & 15) * 4;
        int i1 = s_i1[row], i2 = s_i2[row];
        float a1 = s_a1[row], a2 = s_a2[row];
        float4 v;
        v.x = (j + 0 == i1) ? a1 : ((j + 0 == i2) ? a2 : 0.f);
        v.y = (j + 1 == i1) ? a1 : ((j + 1 == i2) ? a2 : 0.f);
        v.z = (j + 2 == i1) ? a1 : ((j + 2 == i2) ? a2 : 0.f);
        v.w = (j + 3 == i1) ? a1 : ((j + 3 == i2) ? a2 : 0.f);
        *(float4*)(obase + (long)row * K_DIM + j) = v;
    }
}

extern "C" void kernel_launch(void* const* d_in, const int* in_sizes, int n_in,
                              void* d_out, int out_size, void* d_ws, size_t ws_size,
                              hipStream_t stream) {
    const float* z = (const float*)d_in[0];
    const float* W = (const float*)d_in[1];
    const float* b = (const float*)d_in[2];
    float* out = (float*)d_out;
    const int N = in_sizes[0] / D_DIM;           // 8192
    router_kernel<<<dim3(N / BM), dim3(BLOCK), 0, stream>>>(z, W, b, out);
}

// Round 2
// 470.341 us; speedup vs baseline: 1.4125x; 1.4125x over previous
//
#include <hip/hip_runtime.h>
#include <math.h>

// Router: logits = z @ W^T + b ; top-2 sparse softmax per row.
// z: [N=8192, D=4096] fp32, W: [K=64, D=4096] fp32, b: [64] fp32, k=2.
// out: alpha [N, 64] fp32 (zeros except top-2 columns per row).
//
// R2: occupancy fix. R1 had grid=256 (1 block/CU, 1 wave/SIMD) -> latency
// bound (VALUBusy 14%, Occ 11.8%). Now: 512-thread blocks (8 waves), 2 rows
// per wave -> BM=16, grid=512 = 2 blocks/CU = 16 waves/CU. BK=128 halves
// barrier count. Dataflow unchanged: lane = output column, W chunk in LDS
// (zero bank conflicts measured with this padding), z via wave-uniform
// broadcast float4 loads, fp32 accumulation (2 chains/row) so top-2
// selection matches the fp32 numpy reference.

constexpr int D_DIM = 4096;
constexpr int K_DIM = 64;
constexpr int BK    = 128;           // D-chunk per LDS stage
constexpr int RM    = 2;             // rows per wave
constexpr int WAVES = 8;
constexpr int BM    = RM * WAVES;    // 16 rows per block
constexpr int BLOCK = WAVES * 64;    // 512 threads

__global__ __launch_bounds__(BLOCK) void router_kernel(
    const float* __restrict__ z, const float* __restrict__ W,
    const float* __restrict__ bias, float* __restrict__ out)
{
    __shared__ float wtile[K_DIM][BK + 4];     // stride 132 words: conflict-free (measured 0)
    __shared__ float slog[BM][K_DIM + 1];
    __shared__ float s_a1[BM], s_a2[BM];
    __shared__ int   s_i1[BM], s_i2[BM];

    const int tid  = threadIdx.x;
    const int lane = tid & 63;                 // = output column
    const int wave = tid >> 6;
    const long row0 = (long)blockIdx.x * BM + (long)wave * RM;
    const float* zbase = z + row0 * D_DIM;

    float accA[RM], accB[RM];
#pragma unroll
    for (int r = 0; r < RM; ++r) { accA[r] = 0.f; accB[r] = 0.f; }

    for (int d0 = 0; d0 < D_DIM; d0 += BK) {
        // Stage W[0:64][d0:d0+BK] -> wtile, fully coalesced (16B/lane).
#pragma unroll
        for (int i = 0; i < (K_DIM * BK) / (BLOCK * 4); ++i) {   // 4 iters
            int f = tid + i * BLOCK;       // float4 index in [0,2048)
            int k = f >> 5;                // 32 float4 per W row chunk
            int j = (f & 31) * 4;
            const float4 v = *(const float4*)(W + (long)k * D_DIM + d0 + j);
            float* dst = &wtile[k][j];
            dst[0] = v.x; dst[1] = v.y; dst[2] = v.z; dst[3] = v.w;
        }
        __syncthreads();

#pragma unroll
        for (int q = 0; q < BK / 4; ++q) {
            const float4 wv = *(const float4*)&wtile[lane][q * 4];
            const float* zp = zbase + d0 + q * 4;
#pragma unroll
            for (int r = 0; r < RM; ++r) {
                // wave-uniform address: one broadcast 16B request per wave
                const float4 zv = *(const float4*)(zp + (long)r * D_DIM);
                accA[r] = fmaf(wv.x, zv.x, accA[r]);
                accB[r] = fmaf(wv.y, zv.y, accB[r]);
                accA[r] = fmaf(wv.z, zv.z, accA[r]);
                accB[r] = fmaf(wv.w, zv.w, accB[r]);
            }
        }
        __syncthreads();
    }

    // logits -> LDS (+bias)
    const float bv = bias[lane];
#pragma unroll
    for (int r = 0; r < RM; ++r)
        slog[wave * RM + r][lane] = accA[r] + accB[r] + bv;
    __syncthreads();

    // per-row top-2 + 2-term softmax (others underflow to exact 0)
    if (tid < BM) {
        float m1 = -INFINITY, m2 = -INFINITY;
        int i1 = 0, i2 = 0;
        for (int j = 0; j < K_DIM; ++j) {
            float v = slog[tid][j];
            if (v > m1)      { m2 = m1; i2 = i1; m1 = v; i1 = j; }
            else if (v > m2) { m2 = v; i2 = j; }
        }
        float e2  = expf(m2 - m1);
        float inv = 1.f / (1.f + e2);
        s_a1[tid] = inv;
        s_a2[tid] = e2 * inv;
        s_i1[tid] = i1; s_i2[tid] = i2;
    }
    __syncthreads();

    // coalesced float4 store of the sparse alpha tile (256 float4s, 512 thr)
    float* obase = out + (long)blockIdx.x * (BM * K_DIM);
    if (tid < (BM * K_DIM) / 4) {
        int row = tid >> 4;
        int j   = (tid & 15) * 4;
        int i1 = s_i1[row], i2 = s_i2[row];
        float a1 = s_a1[row], a2 = s_a2[row];
        float4 v;
        v.x = (j + 0 == i1) ? a1 : ((j + 0 == i2) ? a2 : 0.f);
        v.y = (j + 1 == i1) ? a1 : ((j + 1 == i2) ? a2 : 0.f);
        v.z = (j + 2 == i1) ? a1 : ((j + 2 == i2) ? a2 : 0.f);
        v.w = (j + 3 == i1) ? a1 : ((j + 3 == i2) ? a2 : 0.f);
        *(float4*)(obase + (long)row * K_DIM + j) = v;
    }
}

extern "C" void kernel_launch(void* const* d_in, const int* in_sizes, int n_in,
                              void* d_out, int out_size, void* d_ws, size_t ws_size,
                              hipStream_t stream) {
    const float* z = (const float*)d_in[0];
    const float* W = (const float*)d_in[1];
    const float* b = (const float*)d_in[2];
    float* out = (float*)d_out;
    const int N = in_sizes[0] / D_DIM;           // 8192
    router_kernel<<<dim3(N / BM), dim3(BLOCK), 0, stream>>>(z, W, b, out);
}